// Round 9
// baseline (6867.115 us; speedup 1.0000x reference)
//
#include <hip/hip_runtime.h>
#include <stdint.h>
#include <stddef.h>

typedef _Float16 f16;
typedef _Float16 f16x8 __attribute__((ext_vector_type(8)));
typedef float f32x4 __attribute__((ext_vector_type(4)));
typedef int i32x4 __attribute__((ext_vector_type(4)));

#define MFMA16(a, b, c) __builtin_amdgcn_mfma_f32_16x16x32_f16((a), (b), (c), 0, 0, 0)

static constexpr int kB = 64;
static constexpr int kT = 256;
static constexpr int kD = 1024;
static constexpr int kH = 1024;
static constexpr int kG = 4096;
static constexpr int kSlot = 64 * 1024;          // f16 elems per h slot [128 owner][64 row][8 unit]
static constexpr int kNSlots = kT + 1;           // 257 slots per layer
static constexpr size_t kHistE = (size_t)kNSlots * kSlot;

__device__ __forceinline__ float fast_sigmoid(float x) {
  return __builtin_amdgcn_rcpf(1.f + __expf(-x));
}
__device__ __forceinline__ float fast_tanh(float x) {
  x = fminf(9.f, fmaxf(-9.f, x));
  const float e = __expf(2.f * x);
  return (e - 1.f) * __builtin_amdgcn_rcpf(e + 1.f);
}

// ---- x [64][256][1024] f32 -> xp[t][owner=d>>3][b][d&7] f16 ----
__global__ void x_perm_cvt(const float* __restrict__ x, f16* __restrict__ xp) {
  const size_t id = (size_t)blockIdx.x * 256 + threadIdx.x;
  const int d8 = (int)(id & 127) << 3;
  const int b = (int)(id >> 7) & 63;
  const int t = (int)(id >> 13);
  const float* s = x + (((size_t)b * kT + t) << 10) + d8;
  float4 a = *(const float4*)(s);
  float4 c = *(const float4*)(s + 4);
  f16x8 o;
  o[0] = (f16)a.x; o[1] = (f16)a.y; o[2] = (f16)a.z; o[3] = (f16)a.w;
  o[4] = (f16)c.x; o[5] = (f16)c.y; o[6] = (f16)c.z; o[7] = (f16)c.w;
  *(f16x8*)(xp + (size_t)t * kSlot + (size_t)(d8 >> 3) * 512 + b * 8) = o;
}

// ---- transpose+convert 4 layers: [1024][4096] f32 -> [4096][1024] f16 ----
__global__ void transpose_cvt_z(const float* __restrict__ src, f16* __restrict__ dst) {
  __shared__ float tile[32][33];
  const int z = blockIdx.z;
  const int c0 = blockIdx.x * 32;
  const int r0 = blockIdx.y * 32;
  const float* s = src + (size_t)z * kD * kG;
  f16* d = dst + (size_t)z * kG * kD;
  for (int rr = threadIdx.y; rr < 32; rr += 8)
    tile[rr][threadIdx.x] = s[(size_t)(r0 + rr) * kG + c0 + threadIdx.x];
  __syncthreads();
  for (int cc = threadIdx.y; cc < 32; cc += 8)
    d[(size_t)(c0 + cc) * kD + r0 + threadIdx.x] = (f16)tile[threadIdx.x][cc];
}

// ---------------- 4-layer pipelined LSTM scan (single dispatch) ----------------
// 512 WGs x 512 thr (8 waves), 2 WGs/CU. layer = (bid&7)>>1 (XCD-affine under
// bid%8 round-robin), wgl = ((bid&7)&1)*64 + (bid>>3) owns units [wgl*8,+8).
// U slice (64 KB, own-term, tight recurrence path) in LDS; W slice (64 KB,
// below-term, 1-iteration slack) streamed from L2 each step (per-XCD W set =
// 64 WGs x 64 KB = 4 MB = L2-resident).
// Waves: bw = w&3 (16 batch rows), kw = w>>2: kw0 = W/below term (+finalize),
// kw1 = U/own term. Flags/publish/poll identical to r8 (proven): owner-block
// h slots, dwordx4 sc0sc1 publish, vmcnt(0) drain, per-(wgl,bw) flags,
// specialized pollers (wave 0: below flags, wave 4: own flags) + LDS ready.
__launch_bounds__(512, 4)
__global__ void lstm_scan4(const f16* __restrict__ xp,
                           const f16* __restrict__ Wt4,
                           const f16* __restrict__ Ut4,
                           f16* __restrict__ hist4,
                           int* __restrict__ flags4,
                           const float* __restrict__ bs4,
                           float* __restrict__ out32) {
  __shared__ f16 Ul[4096 * 8];           // 64 KB: [2 colfrag][32 kkg][64 lane][8]
  __shared__ float red0[4 * 64 * 4];     // kw1 partials
  __shared__ float red1[4 * 64 * 4];
  __shared__ f16 hstage[4][16][8];
  __shared__ int lds_ready[2];

  const int bid = blockIdx.x;
  const int xcd = bid & 7;
  const int layer = xcd >> 1;
  const int wgl = (xcd & 1) * 64 + (bid >> 3);
  const int hbase = wgl * 8;
  const int tid = threadIdx.x;
  const int l = tid & 63, w = tid >> 6;   // w 0..7
  const int lr = l & 15, lq = l >> 4;
  const int bw = w & 3, kw = w >> 2;

  const f16* Wt = Wt4 + (size_t)layer * kG * kD;
  const f16* Ut = Ut4 + (size_t)layer * kG * kD;
  f16* own_hist = hist4 + (size_t)layer * kHistE;
  // below operand base: layer 0 -> xp (slot t); layer >0 -> prev hist slot t+1
  const f16* below_base = layer ? (hist4 + (size_t)(layer - 1) * kHistE + kSlot) : xp;
  int* flags_own = flags4 + layer * 512;
  const int* flags_below = flags4 + (layer ? (layer - 1) * 512 : 0);
  const float* bias = bs4 + layer * kG;

  if (tid == 0) {
    lds_ready[0] = layer ? -1 : (1 << 30);  // below readiness (layer0: always)
    lds_ready[1] = 0;                       // own slot 0 pre-zeroed
  }

  // ---- stage U slice into LDS: frag f = x*2048 + kkg*64 + fl ----
#pragma unroll
  for (int ff = 0; ff < 8; ++ff) {
    const int f = tid * 8 + ff;
    const int xq = f >> 11, kkg = (f >> 6) & 31, fl = f & 63;
    const int flr = fl & 15, flq = fl >> 4;
    const int r = xq * 16 + flr;
    const int grow = (r >> 3) * 1024 + hbase + (r & 7);
    *(f16x8*)&Ul[f * 8] =
        *(const f16x8*)(Ut + (size_t)grow * 1024 + kkg * 32 + flq * 8);
  }

  float bv0 = 0.f, bv1 = 0.f;
  if (kw == 0) {
    bv0 = bias[((lr < 8) ? 0 : 1024) + hbase + (lr & 7)];
    bv1 = bias[((lr < 8) ? 2048 : 3072) + hbase + (lr & 7)];
  }
  __syncthreads();

  const int brow = bw * 16 + lq * 4;
  const int ugl = hbase + (lr & 7);
  const int row = bw * 16 + lr;
  const int* pollp = ((w == 0) ? flags_below : flags_own) + l * 8;
  int* fpub = flags_own + (wgl * 4 + bw);

  // W-frag global bases (kw0): b0 colfrag x=0, b1 x=1
  const int grow0 = (lr >> 3) * 1024 + hbase + (lr & 7);
  const int grow1 = (2 + (lr >> 3)) * 1024 + hbase + (lr & 7);
  const f16* wb0 = Wt + (size_t)grow0 * 1024 + lq * 8;
  const f16* wb1 = Wt + (size_t)grow1 * 1024 + lq * 8;

  float c_reg[4] = {0.f, 0.f, 0.f, 0.f};

#pragma unroll 1
  for (int t = 0; t < kT; ++t) {
    // ---- readiness ----
    if (w == 0) {
      if (layer) {
        const int tgt = t + 1;
        for (;;) {
          i32x4 pa, pb;
          asm volatile("global_load_dwordx4 %0, %2, off sc0 sc1\n\t"
                       "global_load_dwordx4 %1, %3, off sc0 sc1\n\t"
                       "s_waitcnt vmcnt(0)"
                       : "=v"(pa), "=v"(pb) : "v"(pollp), "v"(pollp + 4) : "memory");
          const bool ok = pa[0] >= tgt && pa[1] >= tgt && pa[2] >= tgt && pa[3] >= tgt &&
                          pb[0] >= tgt && pb[1] >= tgt && pb[2] >= tgt && pb[3] >= tgt;
          if (__all(ok)) break;
          __builtin_amdgcn_s_sleep(2);
        }
        __asm__ __volatile__("" ::: "memory");
        *(volatile int*)&lds_ready[0] = t;
      }
    } else if (w == 4) {
      const int tgt = t;
      for (;;) {
        i32x4 pa, pb;
        asm volatile("global_load_dwordx4 %0, %2, off sc0 sc1\n\t"
                     "global_load_dwordx4 %1, %3, off sc0 sc1\n\t"
                     "s_waitcnt vmcnt(0)"
                     : "=v"(pa), "=v"(pb) : "v"(pollp), "v"(pollp + 4) : "memory");
        const bool ok = pa[0] >= tgt && pa[1] >= tgt && pa[2] >= tgt && pa[3] >= tgt &&
                        pb[0] >= tgt && pb[1] >= tgt && pb[2] >= tgt && pb[3] >= tgt;
        if (__all(ok)) break;
        __builtin_amdgcn_s_sleep(2);
      }
      __asm__ __volatile__("" ::: "memory");
      *(volatile int*)&lds_ready[1] = t;
    }
    {
      volatile int* rdy = &lds_ready[kw];
      while (*rdy < t) __builtin_amdgcn_s_sleep(1);
      __asm__ __volatile__("" ::: "memory");
    }

    // ---- this wave's term: K=1024, 32 ii, 64 MFMAs ----
    f32x4 acc0 = {}, acc1 = {};
    if (kw == 0) {
      // below term: A from below slot, B = W streamed from L2
      const f16* hp = below_base + (size_t)t * kSlot + (size_t)lq * 512 + row * 8;
#pragma unroll 1
      for (int base = 0; base < 32; base += 4) {
        f16x8 ha[4], b0[4], b1[4];
#pragma unroll
        for (int j = 0; j < 4; ++j) {
          ha[j] = *(const f16x8*)(hp + (size_t)(base + j) * 2048);
          b0[j] = *(const f16x8*)(wb0 + (base + j) * 32);
          b1[j] = *(const f16x8*)(wb1 + (base + j) * 32);
        }
#pragma unroll
        for (int j = 0; j < 4; ++j) {
          acc0 = MFMA16(ha[j], b0[j], acc0);
          acc1 = MFMA16(ha[j], b1[j], acc1);
        }
      }
    } else {
      // own term: A from own slot t, B = U in LDS
      const f16* hp = own_hist + (size_t)t * kSlot + (size_t)lq * 512 + row * 8;
#pragma unroll 1
      for (int base = 0; base < 32; base += 4) {
        f16x8 ha[4], b0[4], b1[4];
#pragma unroll
        for (int j = 0; j < 4; ++j) {
          ha[j] = *(const f16x8*)(hp + (size_t)(base + j) * 2048);
          b0[j] = *(const f16x8*)&Ul[((base + j) * 64 + l) * 8];
          b1[j] = *(const f16x8*)&Ul[((2048 + (base + j) * 64) + l) * 8];
        }
#pragma unroll
        for (int j = 0; j < 4; ++j) {
          acc0 = MFMA16(ha[j], b0[j], acc0);
          acc1 = MFMA16(ha[j], b1[j], acc1);
        }
      }
    }

    // ---- kw1 partials -> LDS; kw0 reduces + finalizes ----
    if (kw == 1) {
      *(f32x4*)&red0[((w - 4) * 64 + l) * 4] = acc0;
      *(f32x4*)&red1[((w - 4) * 64 + l) * 4] = acc1;
    }
    __syncthreads();

    if (kw == 0) {
      f32x4 s0 = acc0 + *(const f32x4*)&red0[(bw * 64 + l) * 4];
      f32x4 s1 = acc1 + *(const f32x4*)&red1[(bw * 64 + l) * 4];

      float hv[4];
#pragma unroll
      for (int j = 0; j < 4; ++j) {
        const float z0 = s0[j] + bv0;
        const float z1 = s1[j] + bv1;
        const float q0 = __shfl_xor(z0, 8);
        const float q1 = __shfl_xor(z1, 8);
        const float zi = (lr & 8) ? q0 : z0;
        const float zf = (lr & 8) ? z0 : q0;
        const float zg = (lr & 8) ? q1 : z1;
        const float zo = (lr & 8) ? z1 : q1;
        const float iv = fast_sigmoid(zi);
        const float fv = fast_sigmoid(zf);
        const float gv = fast_tanh(zg);
        const float ov = fast_sigmoid(zo);
        const float cn = fv * c_reg[j] + iv * gv;
        c_reg[j] = cn;
        hv[j] = ov * fast_tanh(cn);
      }

      // gather wave's 16 rows x 8 units, coalesced publish (1 dwordx4/lane)
      if (lr < 8) {
#pragma unroll
        for (int j = 0; j < 4; ++j)
          hstage[w][lq * 4 + j][lr] = (f16)hv[j];
      }
      if (l < 16) {
        const f16x8 hrow = *(const f16x8*)&hstage[w][l][0];
        f16* dst = own_hist + (size_t)(t + 1) * kSlot +
                   ((size_t)wgl * 64 + bw * 16 + l) * 8;
        asm volatile("global_store_dwordx4 %0, %1, off sc0 sc1"
                     :: "v"(dst), "v"(hrow) : "memory");
      }
      asm volatile("s_waitcnt vmcnt(0)" ::: "memory");
      if (l == 0) {
        const int val = t + 1;
        asm volatile("global_store_dword %0, %1, off sc0 sc1"
                     :: "v"(fpub), "v"(val) : "memory");
      }
      // final output (layer 3), off critical path
      if (layer == 3 && lr < 8) {
#pragma unroll
        for (int j = 0; j < 4; ++j)
          out32[((size_t)(brow + j) * kT + t) * kH + ugl] = hv[j];
      }
    }
    __syncthreads();   // red buffers reusable next step
  }
}

// ---------------- host launch ----------------
extern "C" void kernel_launch(void* const* d_in, const int* in_sizes, int n_in,
                              void* d_out, int out_size, void* d_ws, size_t ws_size,
                              hipStream_t stream) {
  (void)in_sizes; (void)n_in; (void)out_size; (void)ws_size;
  const float* x = (const float*)d_in[0];
  const float* Ws = (const float*)d_in[1];
  const float* Us = (const float*)d_in[2];
  const float* bs = (const float*)d_in[3];
  char* ws = (char*)d_ws;

  const size_t kLayerW = (size_t)kG * kD * 2;               // 8 MB
  const size_t kHistB = kHistE * 2;                         // 33,685,504 B
  const size_t WT_OFF = 0;                                  // 32 MB
  const size_t UT_OFF = WT_OFF + 4 * kLayerW;               // 32 MB
  const size_t XP_OFF = UT_OFF + 4 * kLayerW;               // 32 MB
  const size_t HH_OFF = XP_OFF + (size_t)kT * kSlot * 2;    // 128.5 MB
  const size_t FL_OFF = HH_OFF + 4 * kHistB;                // 8 KB (total ~225 MB)

  f16* Wt = (f16*)(ws + WT_OFF);
  f16* Ut = (f16*)(ws + UT_OFF);
  f16* xp = (f16*)(ws + XP_OFF);
  f16* hh = (f16*)(ws + HH_OFF);
  int* fl = (int*)(ws + FL_OFF);

  x_perm_cvt<<<8192, 256, 0, stream>>>(x, xp);
  transpose_cvt_z<<<dim3(kG / 32, kD / 32, 4), dim3(32, 8), 0, stream>>>(Ws, Wt);
  transpose_cvt_z<<<dim3(kG / 32, kD / 32, 4), dim3(32, 8), 0, stream>>>(Us, Ut);
  for (int i = 0; i < 4; ++i)
    hipMemsetAsync(ws + HH_OFF + i * kHistB, 0, (size_t)kSlot * 2, stream);
  hipMemsetAsync(ws + FL_OFF, 0, 4 * 512 * 4, stream);

  lstm_scan4<<<512, 512, 0, stream>>>(xp, Wt, Ut, hh, fl, bs, (float*)d_out);
}